// Round 7
// baseline (465.958 us; speedup 1.0000x reference)
//
#include <hip/hip_runtime.h>
#include <hip/hip_cooperative_groups.h>
#include <math.h>

namespace cg = cooperative_groups;

#define NN 2048
#define MAX_ITER 1000
#define TOLF 1e-6f
#define TPB 512
#define NBLK 256
#define WPB 8                  // waves per block; NBLK*WPB == NN (one wave per row)
#define NREP 8                 // replicas of the tagged f words (poll-traffic / 8)
#define SPIN_LIMIT (1 << 14)   // VMEM poll rounds before abort
#define LDS_SPIN_LIMIT (1 << 18)
#define FLAG_ABORT 0x7f000000

// pair word: [63:33]=tag (pass number), [32]=viol bit, [31:0]=f32 bits
__device__ __forceinline__ unsigned long long pack_pair(unsigned int tag,
                                                        unsigned int viol,
                                                        float v) {
    return ((unsigned long long)((tag << 1) | viol) << 32) | (unsigned long long)__float_as_uint(v);
}

__global__ __launch_bounds__(TPB, 1)
void xgr_sinkhorn(const float* __restrict__ Mm,
                  const float* __restrict__ Gg,
                  const int* __restrict__ eps_p,
                  float* __restrict__ out,
                  unsigned long long* __restrict__ ws64)
{
    __shared__ float  m_lds[WPB][NN];   // 64 KB: this block's 8 M rows
    __shared__ float  fA[NN], fB[NN];   // f_t staging, double-buffered by parity
    __shared__ int    sflag[2][WPB];    // per-parity, per-slice validated-tag flags
    __shared__ double s_part[WPB];

    // workspace: NREP replicas x 2 parities x 2048 fused value+tag words.
    // ALL cross-XCD sync rides relaxed atomics on these words — no fences in
    // the loop (agent release/acquire = L2 writeback/invalidate = catastrophic).
    // replica r, parity p base: ws64 + (r*2+p)*NN
    double*       acc      = (double*)(ws64 + NREP * 2 * NN);
    unsigned int* done_cnt = (unsigned int*)(acc + 1);
    unsigned int* abortp   = done_cnt + 1;

    const int tid  = threadIdx.x;
    const int lane = tid & 63;
    const int wave = tid >> 6;
    const int row  = blockIdx.x * WPB + wave;
    const int gtid = blockIdx.x * TPB + tid;
    const int grp  = blockIdx.x >> 5;        // which replica this block polls

    // init: each block inits its own 8 rows in all NREP x 2 buffers
    if (tid < NREP * 2 * WPB) {              // 128 threads
        const int rep = tid >> 4, p = (tid >> 3) & 1, rw = tid & 7;
        const int r = blockIdx.x * WPB + rw;
        ws64[(rep * 2 + p) * NN + r] = p ? 0xFFFFFFFF00000000ULL  // invalid tag
                                         : 0ULL;                  // f_0=0, tag 0
    }
    if (gtid == 0) { *acc = 0.0; *done_cnt = 0u; *abortp = 0u; }
    if (tid < 2 * WPB) ((int*)sflag)[tid] = -1;

    const int ebits = *eps_p;
    const float eps = (ebits >= 1 && ebits <= (1 << 20)) ? (float)ebits
                                                         : __int_as_float(ebits);
    const float inv_eps = 1.0f / eps;

    // stage this block's 8 M rows into LDS (once)
    {
        const float4* Mrow = (const float4*)(Mm + (size_t)row * NN);
        float4* ml4 = (float4*)m_lds[wave];
        #pragma unroll
        for (int k = 0; k < 8; ++k) {
            const int idx = (k << 6) + lane;
            ml4[idx] = Mrow[idx];
        }
    }

    cg::this_grid().sync();   // init visible device-wide; tag protocol takes over

    float* f_final = nullptr;
    bool   aborted = false;

    for (int t = 0; ; ++t) {
        const int p = t & 1;
        float* fl = p ? fB : fA;
        unsigned long long* gb = ws64 + (grp * 2 + p) * NN;   // this block's replica

        // ---- validate + stage OWN slice: wave w owns rows [256w, 256w+256).
        // lane l's 4 words are exactly the columns lane l consumes for chunk w.
        // Paced (s_sleep) poll of one replica -> IF request rate stays unsaturated.
        {
            const unsigned int want = (unsigned int)t;
            unsigned long long* gw = gb + (wave << 8) + (lane << 2);
            unsigned long long pw0 = 0, pw1 = 0, pw2 = 0, pw3 = 0;
            bool ok0 = false, ok1 = false, ok2 = false, ok3 = false;
            int vio = 0, guard = 0;
            for (;;) {
                if (!ok0) { unsigned long long q = __hip_atomic_load(gw + 0, __ATOMIC_RELAXED, __HIP_MEMORY_SCOPE_AGENT);
                            if ((unsigned int)(q >> 33) == want) { ok0 = true; pw0 = q; vio |= (int)((q >> 32) & 1ULL); } }
                if (!ok1) { unsigned long long q = __hip_atomic_load(gw + 1, __ATOMIC_RELAXED, __HIP_MEMORY_SCOPE_AGENT);
                            if ((unsigned int)(q >> 33) == want) { ok1 = true; pw1 = q; vio |= (int)((q >> 32) & 1ULL); } }
                if (!ok2) { unsigned long long q = __hip_atomic_load(gw + 2, __ATOMIC_RELAXED, __HIP_MEMORY_SCOPE_AGENT);
                            if ((unsigned int)(q >> 33) == want) { ok2 = true; pw2 = q; vio |= (int)((q >> 32) & 1ULL); } }
                if (!ok3) { unsigned long long q = __hip_atomic_load(gw + 3, __ATOMIC_RELAXED, __HIP_MEMORY_SCOPE_AGENT);
                            if ((unsigned int)(q >> 33) == want) { ok3 = true; pw3 = q; vio |= (int)((q >> 32) & 1ULL); } }
                if (__all(ok0 && ok1 && ok2 && ok3)) break;
                __builtin_amdgcn_s_sleep(1);          // pace: keep IF unsaturated
                if ((++guard & 63) == 0) {
                    int ab = 0;
                    if (lane == 0) ab = (int)__hip_atomic_load(abortp, __ATOMIC_RELAXED, __HIP_MEMORY_SCOPE_AGENT);
                    ab = __shfl(ab, 0);
                    if (ab || guard > SPIN_LIMIT) {
                        if (lane == 0) __hip_atomic_store(abortp, 1u, __ATOMIC_RELAXED, __HIP_MEMORY_SCOPE_AGENT);
                        aborted = true; break;
                    }
                }
            }
            float4 v;
            v.x = __uint_as_float((unsigned int)pw0);
            v.y = __uint_as_float((unsigned int)pw1);
            v.z = __uint_as_float((unsigned int)pw2);
            v.w = __uint_as_float((unsigned int)pw3);
            ((float4*)(fl + (wave << 8)))[lane] = v;
            const int wv = __any(vio != 0) ? 1 : 0;
            __threadfence_block();   // ds writes visible before flag (block scope: cheap)
            if (lane == 0)
                *(volatile int*)&sflag[p][wave] = aborted ? FLAG_ABORT : ((t << 1) | wv);
        }
        if (aborted) { f_final = fl; break; }   // garbage f -> absmax screams, no hang

        // ---- chunk-pipelined compute, starting at OWN slice (no wait for chunk 0).
        // fmax is exactly commutative/associative; x[] indices and the expf-sum
        // order below are fixed -> bit-identical to rounds 2/4.
        float x[32];
        float mloc = -INFINITY;
        int violall = 0;
        const float4* ml4 = (const float4*)m_lds[wave];
        for (int j = 0; j < WPB; ++j) {
            const int c = (wave + j) & 7;
            volatile int* fp = &sflag[p][c];
            int v = *fp;
            int g = 0;
            while (v < (t << 1)) {
                __builtin_amdgcn_s_sleep(1);
                if ((++g & 1023) == 0) {
                    int ab = 0;
                    if (lane == 0) ab = (int)__hip_atomic_load(abortp, __ATOMIC_RELAXED, __HIP_MEMORY_SCOPE_AGENT);
                    ab = __shfl(ab, 0);
                    if (ab || g > LDS_SPIN_LIMIT) { aborted = true; break; }
                }
                v = *fp;
            }
            if (aborted || v >= FLAG_ABORT) { aborted = true; break; }
            violall |= (v & 1);
            const float4 f4 = ((const float4*)(fl + (c << 8)))[lane];
            const float4 mv = ml4[(c << 6) + lane];
            const float x0 = (f4.x - mv.x) * inv_eps;
            const float x1 = (f4.y - mv.y) * inv_eps;
            const float x2 = (f4.z - mv.z) * inv_eps;
            const float x3 = (f4.w - mv.w) * inv_eps;
            x[4*c+0] = x0; x[4*c+1] = x1; x[4*c+2] = x2; x[4*c+3] = x3;
            mloc = fmaxf(mloc, fmaxf(fmaxf(x0, x1), fmaxf(x2, x3)));
        }
        if (aborted) {
            if (lane == 0) __hip_atomic_store(abortp, 1u, __ATOMIC_RELAXED, __HIP_MEMORY_SCOPE_AGENT);
            f_final = fl; break;
        }

        // convergence: viol bits ride tag-t words (t≡2 mod 10; check at k=t-2 on
        // f_{t-1}); decision uniform across all waves/blocks (same 2048 words).
        if ((t % 10) == 2 && violall == 0) {
            f_final = p ? fA : fB;            // f_{t-1}, staged last pass
            break;
        }
        if (t == MAX_ITER) { f_final = fl; break; }   // f_1000, just staged

        float mw = mloc;
        #pragma unroll
        for (int off = 32; off; off >>= 1)
            mw = fmaxf(mw, __shfl_down(mw, off));
        mw = __shfl(mw, 0);
        float s = 0.0f;
        #pragma unroll
        for (int k = 0; k < 32; ++k) s += expf(x[k] - mw);
        #pragma unroll
        for (int off = 32; off; off >>= 1)
            s += __shfl_down(s, off);

        if (lane == 0) {
            const float L  = mw + logf(s);
            const float fi = fl[row];
            const float fn = 0.5f * (fi - eps * L);
            unsigned int viol = 0u;
            if ((t % 10) == 1) {   // reference check at k=t-1 on f_t
                const float rs = expf(fi * inv_eps + L);
                viol = (fabsf(rs - 1.0f) < TOLF) ? 0u : 1u;
            }
            const unsigned long long w = pack_pair((unsigned int)(t + 1), viol, fn);
            const int pn = (t + 1) & 1;
            #pragma unroll
            for (int r = 0; r < NREP; ++r)    // fan out to all replicas (fire & forget)
                __hip_atomic_store(ws64 + (r * 2 + pn) * NN + row, w,
                                   __ATOMIC_RELAXED, __HIP_MEMORY_SCOPE_AGENT);
        }
        // no barrier: next pass's validation IS the synchronization
    }

    // ---- loss epilogue: sum_ij g*(log g - logQ - 1) + exp(logQ); logQ=(f_i+f_j-M)/eps
    __syncthreads();
    const float4* Grow = (const float4*)(Gg + (size_t)row * NN);
    const float4* ml4  = (const float4*)m_lds[wave];
    const float4* fl4  = (const float4*)f_final;
    const float   fi   = f_final[row];
    double lsum = 0.0;
    #pragma unroll
    for (int k = 0; k < 8; ++k) {
        const int idx = (k << 6) + lane;
        const float4 mv = ml4[idx];
        const float4 gv = Grow[idx];
        const float4 f4 = fl4[idx];
        {
            const float lq = (fi + f4.x - mv.x) * inv_eps;
            lsum += (double)(gv.x * (logf(gv.x) - lq - 1.0f) + expf(lq));
        }
        {
            const float lq = (fi + f4.y - mv.y) * inv_eps;
            lsum += (double)(gv.y * (logf(gv.y) - lq - 1.0f) + expf(lq));
        }
        {
            const float lq = (fi + f4.z - mv.z) * inv_eps;
            lsum += (double)(gv.z * (logf(gv.z) - lq - 1.0f) + expf(lq));
        }
        {
            const float lq = (fi + f4.w - mv.w) * inv_eps;
            lsum += (double)(gv.w * (logf(gv.w) - lq - 1.0f) + expf(lq));
        }
    }
    #pragma unroll
    for (int off = 32; off; off >>= 1)
        lsum += __shfl_down(lsum, off);

    if (lane == 0) s_part[wave] = lsum;
    __syncthreads();
    if (tid == 0) {
        double b = 0.0;
        #pragma unroll
        for (int w = 0; w < WPB; ++w) b += s_part[w];
        atomicAdd(acc, b);
        __threadfence();   // once, outside the loop: amortized to zero
        const unsigned int prev = __hip_atomic_fetch_add(done_cnt, 1u,
                                                         __ATOMIC_RELAXED, __HIP_MEMORY_SCOPE_AGENT);
        if (prev == NBLK - 1) {   // last block finalizes
            __threadfence();
            const double total = __hip_atomic_load(acc, __ATOMIC_RELAXED,
                                                   __HIP_MEMORY_SCOPE_AGENT);
            out[0] = (float)(250.0 * total);
        }
    }
}

extern "C" void kernel_launch(void* const* d_in, const int* in_sizes, int n_in,
                              void* d_out, int out_size, void* d_ws, size_t ws_size,
                              hipStream_t stream)
{
    const float* Mm    = (const float*)d_in[0];
    const float* Gg    = (const float*)d_in[1];
    const int*   eps_p = (const int*)d_in[2];
    float* out = (float*)d_out;
    unsigned long long* ws64 = (unsigned long long*)d_ws;

    void* args[] = { (void*)&Mm, (void*)&Gg, (void*)&eps_p, (void*)&out, (void*)&ws64 };
    hipLaunchCooperativeKernel((void*)xgr_sinkhorn, dim3(NBLK), dim3(TPB),
                               args, 0, stream);
}